// Round 14
// baseline (831.919 us; speedup 1.0000x reference)
//
#include <hip/hip_runtime.h>
#include <stdint.h>

typedef unsigned short u16;
typedef __bf16 bf16_t;
typedef bf16_t bf16x8 __attribute__((ext_vector_type(8)));
typedef float f32x4 __attribute__((ext_vector_type(4)));

#define Bdim 64
#define Tdim 256
#define Ddim 512
#define Hdim 1024
#define NGdim 4096

// ---------- helpers ----------
__device__ __forceinline__ u16 f2bf(float f) {
  union { float f; uint32_t u; } v; v.f = f;
  return (u16)((v.u + 0x7FFFu + ((v.u >> 16) & 1u)) >> 16);   // RNE
}
__device__ __forceinline__ float bf2f(u16 h) {
  union { uint32_t u; float f; } v; v.u = ((uint32_t)h) << 16;
  return v.f;
}
__device__ __forceinline__ float sigm(float x) { return 1.0f / (1.0f + __expf(-x)); }
__device__ __forceinline__ float tanh_fast(float x) { return 2.0f / (1.0f + __expf(-2.0f * x)) - 1.0f; }

__device__ __forceinline__ void load_lds16(const void* g, void* l) {
  __builtin_amdgcn_global_load_lds(
      (const __attribute__((address_space(1))) uint32_t*)g,
      (__attribute__((address_space(3))) uint32_t*)l, 16, 0, 0);
}
__device__ __forceinline__ f32x4 mfma_bf16(bf16x8 a, bf16x8 b, f32x4 c) {
  return __builtin_amdgcn_mfma_f32_16x16x32_bf16(a, b, c, 0, 0, 0);
}

// ---------- kernel 1: merged setup (one launch, 8192 blocks) ----------
// All blocks: x fp32 [b][t][d] -> xb2 bf16 M-major [t*64+b][512]  (R12-verified math).
// Blocks 0..255:   prep_wh chunk (wg = bid>>2, ktg = bid&3)       (R12-verified math).
// Blocks 256..511: prep_wx chunk (wg = (bid-256)>>2, ktg = ...)   (R12-verified math).
// Blocks 512..767: zero h dbuf + flag-slot region (512 KB; flags now 256 x 128 B = 32 KB).
__global__ __launch_bounds__(256) void k_setup(
    const float* __restrict__ x, u16* __restrict__ xb,
    const float* __restrict__ W, u16* __restrict__ whT, u16* __restrict__ whX,
    uint64_t* __restrict__ zreg)
{
  __shared__ float tile[32][68];
  const int bid = blockIdx.x;
  const int tid = threadIdx.x;

  // ---- convert slice (every block) ----
  {
    const int i = (bid * 256 + tid) * 4;
    const int d = i & 511;
    const int t = (i >> 9) & 255;
    const int b = i >> 17;
    float4 v = *(const float4*)(x + i);
    union { u16 h[4]; uint2 v2; } p;
    p.h[0] = f2bf(v.x); p.h[1] = f2bf(v.y); p.h[2] = f2bf(v.z); p.h[3] = f2bf(v.w);
    *(uint2*)(xb + (size_t)(t * 64 + b) * 512 + d) = p.v2;
  }

  if (bid < 256) {
    // ---- prep_wh: whT[wg*65536 + kt*2048 + gate*512 + q*128 + hc*8 + ki]
    //              = bf16(W[(512+kt*32+q*8+ki)*4096 + gate*1024 + wg*16 + hc]) ----
    const int wg  = bid >> 2;
    const int ktg = bid & 3;
    const int lr = tid >> 3, lg = (tid >> 1) & 3, ls = (tid & 1) * 2;
    const int gate = tid >> 6, q = (tid >> 4) & 3, hc = tid & 15;
#pragma unroll 1
    for (int kt = ktg * 8; kt < ktg * 8 + 8; kt++) {
      __syncthreads();
      {
        const float* src = W + (size_t)(Ddim + kt * 32 + lr) * NGdim + lg * 1024 + wg * 16 + ls * 4;
        const float4 v0 = *(const float4*)(src);
        const float4 v1 = *(const float4*)(src + 4);
        *(float4*)&tile[lr][lg * 16 + ls * 4]     = v0;
        *(float4*)&tile[lr][lg * 16 + ls * 4 + 4] = v1;
      }
      __syncthreads();
      union { u16 h[8]; uint4 v; } p;
#pragma unroll
      for (int ki = 0; ki < 8; ki++) p.h[ki] = f2bf(tile[q * 8 + ki][gate * 16 + hc]);
      *(uint4*)(whT + (size_t)wg * 65536 + kt * 2048 + gate * 512 + q * 128 + hc * 8) = p.v;
    }
  } else if (bid < 512) {
    // ---- prep_wx: same structure, W rows [0,512) ----
    const int b2  = bid - 256;
    const int wg  = b2 >> 2;
    const int ktg = b2 & 3;
    const int lr = tid >> 3, lg = (tid >> 1) & 3, ls = (tid & 1) * 2;
    const int gate = tid >> 6, q = (tid >> 4) & 3, hc = tid & 15;
#pragma unroll 1
    for (int kt = ktg * 4; kt < ktg * 4 + 4; kt++) {
      __syncthreads();
      {
        const float* src = W + (size_t)(kt * 32 + lr) * NGdim + lg * 1024 + wg * 16 + ls * 4;
        const float4 v0 = *(const float4*)(src);
        const float4 v1 = *(const float4*)(src + 4);
        *(float4*)&tile[lr][lg * 16 + ls * 4]     = v0;
        *(float4*)&tile[lr][lg * 16 + ls * 4 + 4] = v1;
      }
      __syncthreads();
      union { u16 h[8]; uint4 v; } p;
#pragma unroll
      for (int ki = 0; ki < 8; ki++) p.h[ki] = f2bf(tile[q * 8 + ki][gate * 16 + hc]);
      *(uint4*)(whX + (size_t)wg * 32768 + kt * 2048 + gate * 512 + q * 128 + hc * 8) = p.v;
    }
  } else if (bid < 768) {
    // ---- zero h dbuf + flag slots (512 KB) ----
    zreg[(size_t)(bid - 512) * 256 + tid] = 0ull;
  }
}

// ---------- kernel 2: persistent LSTM with FUSED x@Wx ----------
// R13-verified base; ONE delta: flag slots spread to 128 B per producer (slot = gid*32 u32)
// to eliminate the 64-writers-to-2-LLC-lines store serialization of the packed layout.
// Poll = each lane loads its own producer's slot (one wave instruction, 64 parallel lines).
// Protocol otherwise byte-identical: producers publish one contiguous 512 B h block (agent
// write-through) -> vmcnt(0) -> relaxed agent flag; wave0 polls own group's 64 flags ->
// __syncthreads -> sc0 sc1 h loads; split vmcnt(4)/vmcnt(0) around MFMA halves.
__global__ __launch_bounds__(256, 1) void k_lstm_persist(
    const u16* __restrict__ whT, const u16* __restrict__ whX,
    const u16* __restrict__ xb, const int* __restrict__ seq_len,
    u16* __restrict__ hbuf, uint32_t* __restrict__ flags,
    const float* __restrict__ bias, float* __restrict__ out)
{
  __shared__ float zlds[64 * 66];              // [wave*16+m][66 (pad)]
  __shared__ __align__(8) u16 hpack[16][16];   // [local batch][local hcol]
  __shared__ u16 wxlds[32768];                 // 64 KB Wx fragment slice for this wg
  const int gid   = blockIdx.x;
  const int g_grp = gid >> 6;           // batch group 0..3
  const int wg    = gid & 63;           // h-col owner within group
  const int tid   = threadIdx.x;
  const int lane  = tid & 63;
  const int wave  = tid >> 6;
  const int q     = lane >> 4;
  const int col   = lane & 15;
  const int b_t   = tid & 15;           // owned local batch
  const int hc_t  = tid >> 4;           // owned local hcol
  const int g16   = g_grp * 16;

  // stationary W_h weights: wave covers K_h [wave*256, wave*256+256)
  bf16x8 bw[8][4];
  {
    const u16* wp = whT + (size_t)wg * 65536 + (size_t)(q * 16 + col) * 8;
#pragma unroll
    for (int kt = 0; kt < 8; kt++)
#pragma unroll
      for (int g = 0; g < 4; g++)
        bw[kt][g] = *(const bf16x8*)(wp + (wave * 8 + kt) * 2048 + g * 512);
  }

  // stage this wg's Wx fragment slice (64 KB) into LDS, linear copy (16 chunks/wave of 1 KB)
  {
    const u16* src = whX + (size_t)wg * 32768;
#pragma unroll
    for (int i = 0; i < 16; i++) {
      const int chunk = i * 4 + wave;          // 0..63, 512 u16 each
      load_lds16(src + (size_t)chunk * 512 + lane * 8, wxlds + chunk * 512);
    }
  }

  // per-thread bias for owned (hcol, 4 gates)
  float bi[4];
#pragma unroll
  for (int g = 0; g < 4; g++) bi[g] = bias[g * 1024 + wg * 16 + hc_t];

  const int slen = seq_len[g16 + b_t];
  float c_reg = 0.f, h_reg = 0.f;

  // producer-major h base: producer p = wave*16 + kt*2 + (q>>1), batch = col,
  // elem (q&1)*8 + j. u16 offset: parity*65536 + g_grp*16384 + p*256 + col*16 + (q&1)*8
  const u16* pa0 = hbuf + (size_t)g_grp * 16384
                 + (size_t)(wave * 16 + (q >> 1)) * 256 + col * 16 + (q & 1) * 8;
  // x A-frag base: row = t*64 + g16+col (M-major), k = wave*128 + j*32 + q*8
  const u16* px0 = xb + (size_t)(g16 + col) * 512 + wave * 128 + q * 8;

  __syncthreads();   // wxlds staged (compiler drains vmcnt before barrier)

  for (int t = 0; t < Tdim; t++) {
    // ---- x-part (h-independent): overlaps the poll wait ----
    const u16* px = px0 + (size_t)t * 32768;   // t*64 rows * 512
    f32x4 axv[4];
#pragma unroll
    for (int j = 0; j < 4; j++)
      asm volatile("global_load_dwordx4 %0, %1, off" : "=v"(axv[j]) : "v"(px + j * 32));
    asm volatile("s_waitcnt vmcnt(0)" ::: "memory");
    __builtin_amdgcn_sched_barrier(0);

    const f32x4 zero4 = {0.f, 0.f, 0.f, 0.f};
    f32x4 acc[4] = {zero4, zero4, zero4, zero4};
#pragma unroll
    for (int j = 0; j < 4; j++)
#pragma unroll
      for (int g = 0; g < 4; g++) {
        const bf16x8 bx = *(const bf16x8*)(wxlds + (wave * 4 + j) * 2048
                                           + g * 512 + q * 128 + col * 8);
        acc[g] = mfma_bf16(__builtin_bit_cast(bf16x8, axv[j]), bx, acc[g]);
      }

    if (t > 0) {
      if (wave == 0) {
        const uint32_t gen = (uint32_t)t;
        // spread flag slots: lane polls producer (g_grp*64 + lane)'s own 128-B slot
        const uint32_t* fp = flags + ((size_t)(g_grp * 64 + lane) << 5);
        uint32_t f;
        do {
          f = __hip_atomic_load(fp, __ATOMIC_RELAXED, __HIP_MEMORY_SCOPE_AGENT);
        } while (!__all(f >= gen));
      }
      __syncthreads();   // barrier between flag observation and h reads (R7-verified)
    }

    // ---- h-part: coherent (LLC) loads, producer-major contiguous ----
    const u16* pa_t = pa0 + (size_t)(t & 1) * 65536;
    f32x4 av[8];
#pragma unroll
    for (int kt = 0; kt < 8; kt++)
      asm volatile("global_load_dwordx4 %0, %1, off sc0 sc1"
                   : "=v"(av[kt]) : "v"(pa_t + kt * 512));
    asm volatile("s_waitcnt vmcnt(4)" ::: "memory");
    __builtin_amdgcn_sched_barrier(0);   // rule #18
#pragma unroll
    for (int kt = 0; kt < 4; kt++)
#pragma unroll
      for (int g = 0; g < 4; g++)
        acc[g] = mfma_bf16(__builtin_bit_cast(bf16x8, av[kt]), bw[kt][g], acc[g]);
    asm volatile("s_waitcnt vmcnt(0)" ::: "memory");
    __builtin_amdgcn_sched_barrier(0);
#pragma unroll
    for (int kt = 4; kt < 8; kt++)
#pragma unroll
      for (int g = 0; g < 4; g++)
        acc[g] = mfma_bf16(__builtin_bit_cast(bf16x8, av[kt]), bw[kt][g], acc[g]);

    // partial z (x+h) -> LDS (C/D: n = lane&15, m = q*4+i)
#pragma unroll
    for (int g = 0; g < 4; g++)
#pragma unroll
      for (int i = 0; i < 4; i++)
        zlds[(wave * 16 + q * 4 + i) * 66 + g * 16 + col] = acc[g][i];
    __syncthreads();

    // cross-wave K-reduction + bias; thread owns (b_t, wg*16 + hc_t)
    float zg[4];
#pragma unroll
    for (int g = 0; g < 4; g++) {
      float s = bi[g];
#pragma unroll
      for (int w = 0; w < 4; w++)
        s += zlds[(w * 16 + b_t) * 66 + g * 16 + hc_t];
      zg[g] = s;
    }
    if (t < slen) {
      c_reg = c_reg * sigm(zg[2] + 1.0f) + sigm(zg[0]) * tanh_fast(zg[1]);
      h_reg = tanh_fast(c_reg) * sigm(zg[3]);
    }

    if (t == Tdim - 1) break;   // final h stays in registers

    // publish h slice: ONE contiguous 512 B block, drain, then flag (R9-verified)
    hpack[b_t][hc_t] = f2bf(h_reg);
    __syncthreads();            // orders all zlds reads before next-step rewrites
    if (wave == 0) {
      const int pb = lane >> 2, ph = (lane & 3) * 4;
      const uint64_t pk = *(const uint64_t*)(&hpack[pb][ph]);
      u16* daddr = hbuf + (size_t)((t + 1) & 1) * 65536 + g_grp * 16384
                 + wg * 256 + pb * 16 + ph;
      __hip_atomic_store((uint64_t*)daddr, pk,
                         __ATOMIC_RELAXED, __HIP_MEMORY_SCOPE_AGENT);
      asm volatile("s_waitcnt vmcnt(0)" ::: "memory");   // h at coherence point
      if (lane == 0)
        __hip_atomic_store(flags + ((size_t)gid << 5), (uint32_t)(t + 1),
                           __ATOMIC_RELAXED, __HIP_MEMORY_SCOPE_AGENT);
    }
  }

  out[(size_t)(g16 + b_t) * Hdim + wg * 16 + hc_t] = h_reg;
}

// ---------- host ----------
extern "C" void kernel_launch(void* const* d_in, const int* in_sizes, int n_in,
                              void* d_out, int out_size, void* d_ws, size_t ws_size,
                              hipStream_t stream) {
  (void)in_sizes; (void)n_in; (void)out_size; (void)ws_size;
  const float* x       = (const float*)d_in[0];
  const int*   seq_len = (const int*)d_in[1];
  const float* W       = (const float*)d_in[2];
  const float* bias    = (const float*)d_in[3];
  float* out = (float*)d_out;

  char* ws = (char*)d_ws;
  u16*   xb   = (u16*)(ws);                                  // 16 MB  xb2 bf16 [t*64+b][512]
  u16*   whT  = (u16*)(ws + (size_t)16777216);               // 8 MB   W_h fragments [64][65536]
  u16*   whX  = (u16*)(ws + (size_t)25165824);               // 4 MB   W_x fragments [64][32768]
  char*  hreg = ws + (size_t)29360128;                       // 256 KB h dbuf + 32 KB flag slots
  u16*   hbuf = (u16*)hreg;
  uint32_t* flags = (uint32_t*)(hreg + 262144);              // 256 x 128 B spread slots

  k_setup<<<dim3(8192), dim3(256), 0, stream>>>(x, xb, W, whT, whX, (uint64_t*)hreg);

  {
    void* kargs[] = { (void*)&whT, (void*)&whX, (void*)&xb, (void*)&seq_len,
                      (void*)&hbuf, (void*)&flags, (void*)&bias, (void*)&out };
    hipLaunchCooperativeKernel((const void*)k_lstm_persist, dim3(256), dim3(256),
                               kargs, 0, stream);
  }
}

// Round 15
// 825.938 us; speedup vs baseline: 1.0072x; 1.0072x over previous
//
#include <hip/hip_runtime.h>
#include <stdint.h>

typedef unsigned short u16;
typedef __bf16 bf16_t;
typedef bf16_t bf16x8 __attribute__((ext_vector_type(8)));
typedef float f32x4 __attribute__((ext_vector_type(4)));

#define Bdim 64
#define Tdim 256
#define Ddim 512
#define Hdim 1024
#define NGdim 4096

// ---------- helpers ----------
__device__ __forceinline__ u16 f2bf(float f) {
  union { float f; uint32_t u; } v; v.f = f;
  return (u16)((v.u + 0x7FFFu + ((v.u >> 16) & 1u)) >> 16);   // RNE
}
__device__ __forceinline__ float bf2f(u16 h) {
  union { uint32_t u; float f; } v; v.u = ((uint32_t)h) << 16;
  return v.f;
}
__device__ __forceinline__ float sigm(float x) { return 1.0f / (1.0f + __expf(-x)); }
__device__ __forceinline__ float tanh_fast(float x) { return 2.0f / (1.0f + __expf(-2.0f * x)) - 1.0f; }

__device__ __forceinline__ void load_lds16(const void* g, void* l) {
  __builtin_amdgcn_global_load_lds(
      (const __attribute__((address_space(1))) uint32_t*)g,
      (__attribute__((address_space(3))) uint32_t*)l, 16, 0, 0);
}
__device__ __forceinline__ f32x4 mfma_bf16(bf16x8 a, bf16x8 b, f32x4 c) {
  return __builtin_amdgcn_mfma_f32_16x16x32_bf16(a, b, c, 0, 0, 0);
}

// ---------- kernel 1: merged setup (one launch, 8192 blocks) ----------
// All blocks: x fp32 [b][t][d] -> xb2 bf16 M-major [t*64+b][512]  (R12-verified math).
// Blocks 0..255:   prep_wh chunk (wg = bid>>2, ktg = bid&3)       (R12-verified math).
// Blocks 256..511: prep_wx chunk (wg = (bid-256)>>2, ktg = ...)   (R12-verified math).
// Blocks 512..767: zero h dbuf + flags region (512 KB).
__global__ __launch_bounds__(256) void k_setup(
    const float* __restrict__ x, u16* __restrict__ xb,
    const float* __restrict__ W, u16* __restrict__ whT, u16* __restrict__ whX,
    uint64_t* __restrict__ zreg)
{
  __shared__ float tile[32][68];
  const int bid = blockIdx.x;
  const int tid = threadIdx.x;

  // ---- convert slice (every block) ----
  {
    const int i = (bid * 256 + tid) * 4;
    const int d = i & 511;
    const int t = (i >> 9) & 255;
    const int b = i >> 17;
    float4 v = *(const float4*)(x + i);
    union { u16 h[4]; uint2 v2; } p;
    p.h[0] = f2bf(v.x); p.h[1] = f2bf(v.y); p.h[2] = f2bf(v.z); p.h[3] = f2bf(v.w);
    *(uint2*)(xb + (size_t)(t * 64 + b) * 512 + d) = p.v2;
  }

  if (bid < 256) {
    // ---- prep_wh: whT[wg*65536 + kt*2048 + gate*512 + q*128 + hc*8 + ki]
    //              = bf16(W[(512+kt*32+q*8+ki)*4096 + gate*1024 + wg*16 + hc]) ----
    const int wg  = bid >> 2;
    const int ktg = bid & 3;
    const int lr = tid >> 3, lg = (tid >> 1) & 3, ls = (tid & 1) * 2;
    const int gate = tid >> 6, q = (tid >> 4) & 3, hc = tid & 15;
#pragma unroll 1
    for (int kt = ktg * 8; kt < ktg * 8 + 8; kt++) {
      __syncthreads();
      {
        const float* src = W + (size_t)(Ddim + kt * 32 + lr) * NGdim + lg * 1024 + wg * 16 + ls * 4;
        const float4 v0 = *(const float4*)(src);
        const float4 v1 = *(const float4*)(src + 4);
        *(float4*)&tile[lr][lg * 16 + ls * 4]     = v0;
        *(float4*)&tile[lr][lg * 16 + ls * 4 + 4] = v1;
      }
      __syncthreads();
      union { u16 h[8]; uint4 v; } p;
#pragma unroll
      for (int ki = 0; ki < 8; ki++) p.h[ki] = f2bf(tile[q * 8 + ki][gate * 16 + hc]);
      *(uint4*)(whT + (size_t)wg * 65536 + kt * 2048 + gate * 512 + q * 128 + hc * 8) = p.v;
    }
  } else if (bid < 512) {
    // ---- prep_wx: same structure, W rows [0,512) ----
    const int b2  = bid - 256;
    const int wg  = b2 >> 2;
    const int ktg = b2 & 3;
    const int lr = tid >> 3, lg = (tid >> 1) & 3, ls = (tid & 1) * 2;
    const int gate = tid >> 6, q = (tid >> 4) & 3, hc = tid & 15;
#pragma unroll 1
    for (int kt = ktg * 4; kt < ktg * 4 + 4; kt++) {
      __syncthreads();
      {
        const float* src = W + (size_t)(kt * 32 + lr) * NGdim + lg * 1024 + wg * 16 + ls * 4;
        const float4 v0 = *(const float4*)(src);
        const float4 v1 = *(const float4*)(src + 4);
        *(float4*)&tile[lr][lg * 16 + ls * 4]     = v0;
        *(float4*)&tile[lr][lg * 16 + ls * 4 + 4] = v1;
      }
      __syncthreads();
      union { u16 h[8]; uint4 v; } p;
#pragma unroll
      for (int ki = 0; ki < 8; ki++) p.h[ki] = f2bf(tile[q * 8 + ki][gate * 16 + hc]);
      *(uint4*)(whX + (size_t)wg * 32768 + kt * 2048 + gate * 512 + q * 128 + hc * 8) = p.v;
    }
  } else if (bid < 768) {
    // ---- zero h dbuf + flags (512 KB) ----
    zreg[(size_t)(bid - 512) * 256 + tid] = 0ull;
  }
}

// ---------- kernel 2: persistent LSTM with FUSED x@Wx (R13-VERIFIED, byte-identical) ----------
// Sync protocol: producers publish one contiguous 512 B h block (agent write-through) ->
// vmcnt(0) -> relaxed agent flag (PACKED 4-B stride: R14 showed spread slots cost +21 us
// in poll fetch traffic); wave0 polls own group's 64 flags -> __syncthreads -> sc0 sc1
// h loads; split vmcnt(4)/vmcnt(0) around MFMA halves. x@Wx computed in-loop before the
// poll (h-independent), accumulating into the same acc[g].
__global__ __launch_bounds__(256, 1) void k_lstm_persist(
    const u16* __restrict__ whT, const u16* __restrict__ whX,
    const u16* __restrict__ xb, const int* __restrict__ seq_len,
    u16* __restrict__ hbuf, uint32_t* __restrict__ flags,
    const float* __restrict__ bias, float* __restrict__ out)
{
  __shared__ float zlds[64 * 66];              // [wave*16+m][66 (pad)]
  __shared__ __align__(8) u16 hpack[16][16];   // [local batch][local hcol]
  __shared__ u16 wxlds[32768];                 // 64 KB Wx fragment slice for this wg
  const int gid   = blockIdx.x;
  const int g_grp = gid >> 6;           // batch group 0..3
  const int wg    = gid & 63;           // h-col owner within group
  const int tid   = threadIdx.x;
  const int lane  = tid & 63;
  const int wave  = tid >> 6;
  const int q     = lane >> 4;
  const int col   = lane & 15;
  const int b_t   = tid & 15;           // owned local batch
  const int hc_t  = tid >> 4;           // owned local hcol
  const int g16   = g_grp * 16;

  // stationary W_h weights: wave covers K_h [wave*256, wave*256+256)
  bf16x8 bw[8][4];
  {
    const u16* wp = whT + (size_t)wg * 65536 + (size_t)(q * 16 + col) * 8;
#pragma unroll
    for (int kt = 0; kt < 8; kt++)
#pragma unroll
      for (int g = 0; g < 4; g++)
        bw[kt][g] = *(const bf16x8*)(wp + (wave * 8 + kt) * 2048 + g * 512);
  }

  // stage this wg's Wx fragment slice (64 KB) into LDS, linear copy (16 chunks/wave of 1 KB)
  {
    const u16* src = whX + (size_t)wg * 32768;
#pragma unroll
    for (int i = 0; i < 16; i++) {
      const int chunk = i * 4 + wave;          // 0..63, 512 u16 each
      load_lds16(src + (size_t)chunk * 512 + lane * 8, wxlds + chunk * 512);
    }
  }

  // per-thread bias for owned (hcol, 4 gates)
  float bi[4];
#pragma unroll
  for (int g = 0; g < 4; g++) bi[g] = bias[g * 1024 + wg * 16 + hc_t];

  const int slen = seq_len[g16 + b_t];
  float c_reg = 0.f, h_reg = 0.f;

  // producer-major h base: producer p = wave*16 + kt*2 + (q>>1), batch = col,
  // elem (q&1)*8 + j. u16 offset: parity*65536 + g_grp*16384 + p*256 + col*16 + (q&1)*8
  const u16* pa0 = hbuf + (size_t)g_grp * 16384
                 + (size_t)(wave * 16 + (q >> 1)) * 256 + col * 16 + (q & 1) * 8;
  // x A-frag base: row = t*64 + g16+col (M-major), k = wave*128 + j*32 + q*8
  const u16* px0 = xb + (size_t)(g16 + col) * 512 + wave * 128 + q * 8;

  __syncthreads();   // wxlds staged (compiler drains vmcnt before barrier)

  for (int t = 0; t < Tdim; t++) {
    // ---- x-part (h-independent): overlaps the poll wait ----
    const u16* px = px0 + (size_t)t * 32768;   // t*64 rows * 512
    f32x4 axv[4];
#pragma unroll
    for (int j = 0; j < 4; j++)
      asm volatile("global_load_dwordx4 %0, %1, off" : "=v"(axv[j]) : "v"(px + j * 32));
    asm volatile("s_waitcnt vmcnt(0)" ::: "memory");
    __builtin_amdgcn_sched_barrier(0);

    const f32x4 zero4 = {0.f, 0.f, 0.f, 0.f};
    f32x4 acc[4] = {zero4, zero4, zero4, zero4};
#pragma unroll
    for (int j = 0; j < 4; j++)
#pragma unroll
      for (int g = 0; g < 4; g++) {
        const bf16x8 bx = *(const bf16x8*)(wxlds + (wave * 4 + j) * 2048
                                           + g * 512 + q * 128 + col * 8);
        acc[g] = mfma_bf16(__builtin_bit_cast(bf16x8, axv[j]), bx, acc[g]);
      }

    if (t > 0) {
      if (wave == 0) {
        const uint32_t gen = (uint32_t)t;
        const uint32_t* fp = flags + g_grp * 64 + lane;   // packed: 64 flags = 4 lines
        uint32_t f;
        do {
          f = __hip_atomic_load(fp, __ATOMIC_RELAXED, __HIP_MEMORY_SCOPE_AGENT);
        } while (!__all(f >= gen));
      }
      __syncthreads();   // barrier between flag observation and h reads (R7-verified)
    }

    // ---- h-part: coherent (LLC) loads, producer-major contiguous ----
    const u16* pa_t = pa0 + (size_t)(t & 1) * 65536;
    f32x4 av[8];
#pragma unroll
    for (int kt = 0; kt < 8; kt++)
      asm volatile("global_load_dwordx4 %0, %1, off sc0 sc1"
                   : "=v"(av[kt]) : "v"(pa_t + kt * 512));
    asm volatile("s_waitcnt vmcnt(4)" ::: "memory");
    __builtin_amdgcn_sched_barrier(0);   // rule #18
#pragma unroll
    for (int kt = 0; kt < 4; kt++)
#pragma unroll
      for (int g = 0; g < 4; g++)
        acc[g] = mfma_bf16(__builtin_bit_cast(bf16x8, av[kt]), bw[kt][g], acc[g]);
    asm volatile("s_waitcnt vmcnt(0)" ::: "memory");
    __builtin_amdgcn_sched_barrier(0);
#pragma unroll
    for (int kt = 4; kt < 8; kt++)
#pragma unroll
      for (int g = 0; g < 4; g++)
        acc[g] = mfma_bf16(__builtin_bit_cast(bf16x8, av[kt]), bw[kt][g], acc[g]);

    // partial z (x+h) -> LDS (C/D: n = lane&15, m = q*4+i)
#pragma unroll
    for (int g = 0; g < 4; g++)
#pragma unroll
      for (int i = 0; i < 4; i++)
        zlds[(wave * 16 + q * 4 + i) * 66 + g * 16 + col] = acc[g][i];
    __syncthreads();

    // cross-wave K-reduction + bias; thread owns (b_t, wg*16 + hc_t)
    float zg[4];
#pragma unroll
    for (int g = 0; g < 4; g++) {
      float s = bi[g];
#pragma unroll
      for (int w = 0; w < 4; w++)
        s += zlds[(w * 16 + b_t) * 66 + g * 16 + hc_t];
      zg[g] = s;
    }
    if (t < slen) {
      c_reg = c_reg * sigm(zg[2] + 1.0f) + sigm(zg[0]) * tanh_fast(zg[1]);
      h_reg = tanh_fast(c_reg) * sigm(zg[3]);
    }

    if (t == Tdim - 1) break;   // final h stays in registers

    // publish h slice: ONE contiguous 512 B block, drain, then flag (R9-verified)
    hpack[b_t][hc_t] = f2bf(h_reg);
    __syncthreads();            // orders all zlds reads before next-step rewrites
    if (wave == 0) {
      const int pb = lane >> 2, ph = (lane & 3) * 4;
      const uint64_t pk = *(const uint64_t*)(&hpack[pb][ph]);
      u16* daddr = hbuf + (size_t)((t + 1) & 1) * 65536 + g_grp * 16384
                 + wg * 256 + pb * 16 + ph;
      __hip_atomic_store((uint64_t*)daddr, pk,
                         __ATOMIC_RELAXED, __HIP_MEMORY_SCOPE_AGENT);
      asm volatile("s_waitcnt vmcnt(0)" ::: "memory");   // h at coherence point
      if (lane == 0)
        __hip_atomic_store(flags + gid, (uint32_t)(t + 1),
                           __ATOMIC_RELAXED, __HIP_MEMORY_SCOPE_AGENT);
    }
  }

  out[(size_t)(g16 + b_t) * Hdim + wg * 16 + hc_t] = h_reg;
}

// ---------- host ----------
extern "C" void kernel_launch(void* const* d_in, const int* in_sizes, int n_in,
                              void* d_out, int out_size, void* d_ws, size_t ws_size,
                              hipStream_t stream) {
  (void)in_sizes; (void)n_in; (void)out_size; (void)ws_size;
  const float* x       = (const float*)d_in[0];
  const int*   seq_len = (const int*)d_in[1];
  const float* W       = (const float*)d_in[2];
  const float* bias    = (const float*)d_in[3];
  float* out = (float*)d_out;

  char* ws = (char*)d_ws;
  u16*   xb   = (u16*)(ws);                                  // 16 MB  xb2 bf16 [t*64+b][512]
  u16*   whT  = (u16*)(ws + (size_t)16777216);               // 8 MB   W_h fragments [64][65536]
  u16*   whX  = (u16*)(ws + (size_t)25165824);               // 4 MB   W_x fragments [64][32768]
  char*  hreg = ws + (size_t)29360128;                       // 256 KB h dbuf (producer-major) + flags
  u16*   hbuf = (u16*)hreg;
  uint32_t* flags = (uint32_t*)(hreg + 262144);              // 256 x 4 B packed

  k_setup<<<dim3(8192), dim3(256), 0, stream>>>(x, xb, W, whT, whX, (uint64_t*)hreg);

  {
    void* kargs[] = { (void*)&whT, (void*)&whX, (void*)&xb, (void*)&seq_len,
                      (void*)&hbuf, (void*)&flags, (void*)&bias, (void*)&out };
    hipLaunchCooperativeKernel((const void*)k_lstm_persist, dim3(256), dim3(256),
                               kargs, 0, stream);
  }
}